// Round 10
// baseline (22.937 us; speedup 1.0000x reference)
//
#include <hip/hip_runtime.h>
#include <math.h>

// Problem constants: N=32, CI=32, CO=32, H=64, W=64, K=2
#define NN 32
#define CI 32
#define CO 32
#define HH 64
#define WW 64
#define PLANE (HH * WW)

typedef __attribute__((ext_vector_type(8))) short bf16x8;   // MFMA A/B frag
typedef __attribute__((ext_vector_type(4))) float f32x4;    // MFMA C/D frag

// float -> bf16 (round-to-nearest-even)
__device__ inline short f2bf(float f) {
    union { float f; unsigned u; } v; v.f = f;
    unsigned r = v.u + 0x7FFFu + ((v.u >> 16) & 1u);
    return (short)(r >> 16);
}

// ---------------------------------------------------------------------------
// MEASUREMENT ROUND (R10): kernel is byte-identical to R9 (14.02 us).
// It is dispatched TWICE back-to-back (deterministic: second run recomputes
// the identical output from unchanged inputs). Purpose:
//   marginal kernel cost = dur_us(2x) - 14.02
// separating the suspected ~9-11 us fixed per-replay overhead from the true
// kernel time, and (bonus) pushing two profiled dispatches into the top-5
// counter table (fills sit at ~40-45 us) so we finally see VALUBusy /
// FETCH / occupancy for the MFMA kernel.
//
// Fork, pre-committed:
//   dur ~17-19 -> kernel ~3-5 us, fixed ~10 us -> at real roofline.
//   dur ~24-27 -> kernel ~11 us -> counters say which pipe to attack next.
// ---------------------------------------------------------------------------
__global__ __launch_bounds__(256, 4) void sumconv_mfma(
        const float* __restrict__ x,
        const float* __restrict__ logits,
        float* __restrict__ out) {
    const int b = blockIdx.x;                     // 0..1023
    const int n = (b & 7) * 4 + ((b >> 3) & 3);   // image (XCD-chunked)
    const int r = b >> 5;                         // row-pair 0..31

    const int t    = threadIdx.x;
    const int wave = t >> 6;                      // 0..3 = parity
    const int lane = t & 63;
    const int pr = wave >> 1, pc = wave & 1;
    const int l15 = lane & 15, kb = lane >> 4;
    const int h = 2 * r + pr;

    __shared__ short Wl[4][CO * CI];              // bf16 weights [par][co*32+ci], 8 KB

    // ---- x loads first: 16 independent VMEM ----
    const float* xp = x + ((n * CI + kb * 8) * HH + h) * WW + 2 * l15 + pc;
    float ev0[8], ev1[8];
#pragma unroll
    for (int i = 0; i < 8; ++i) ev0[i] = xp[i * PLANE];        // px cols 0..31
#pragma unroll
    for (int i = 0; i < 8; ++i) ev1[i] = xp[i * PLANE + 32];   // px cols 32..63

    // ---- phase 0: softmax -> LDS bf16 (128 active threads) ----
    if (t < 128) {
        const int co = t >> 2, par = t & 3;
        const float* base = logits + (co * CI) * 4 + par;
        float e[CI];
        float ssum = 0.0f;
#pragma unroll
        for (int ci = 0; ci < CI; ++ci) { e[ci] = __expf(base[ci * 4]); ssum += e[ci]; }
        const float inv = 1.0f / ssum;
#pragma unroll
        for (int ci = 0; ci < CI; ++ci) Wl[par][co * CI + ci] = f2bf(e[ci] * inv);
    }
    __syncthreads();

    // ---- A-frags: one aligned ds_read_b128 per co-half ----
    const bf16x8 afr0 = *(const bf16x8*)&Wl[wave][(l15     ) * CI + kb * 8];
    const bf16x8 afr1 = *(const bf16x8*)&Wl[wave][(l15 + 16) * CI + kb * 8];

    // ---- exp(x) -> bf16 B-frags ----
    bf16x8 bfr0, bfr1;
#pragma unroll
    for (int i = 0; i < 8; ++i) {
        bfr0[i] = f2bf(__expf(ev0[i]));
        bfr1[i] = f2bf(__expf(ev1[i]));
    }

    // ---- 4 MFMAs (K=32 each) ----
    const f32x4 z = {0.f, 0.f, 0.f, 0.f};
    f32x4 a00 = __builtin_amdgcn_mfma_f32_16x16x32_bf16(afr0, bfr0, z, 0, 0, 0);
    f32x4 a01 = __builtin_amdgcn_mfma_f32_16x16x32_bf16(afr0, bfr1, z, 0, 0, 0);
    f32x4 a10 = __builtin_amdgcn_mfma_f32_16x16x32_bf16(afr1, bfr0, z, 0, 0, 0);
    f32x4 a11 = __builtin_amdgcn_mfma_f32_16x16x32_bf16(afr1, bfr1, z, 0, 0, 0);

    // ---- log + store. D: col=l15 (px), row=4*kb+reg (co) ----
    const int wc0 = 2 * l15 + pc;
    float* ob = out + ((n * CO + 4 * kb) * HH + h) * WW;      // co base 4*kb
#pragma unroll
    for (int reg = 0; reg < 4; ++reg) {
        ob[(reg     ) * PLANE + wc0     ] = __logf(a00[reg]);   // co = 4kb+reg
        ob[(reg     ) * PLANE + wc0 + 32] = __logf(a01[reg]);
        ob[(reg + 16) * PLANE + wc0     ] = __logf(a10[reg]);   // co = 16+4kb+reg
        ob[(reg + 16) * PLANE + wc0 + 32] = __logf(a11[reg]);
    }
}

extern "C" void kernel_launch(void* const* d_in, const int* in_sizes, int n_in,
                              void* d_out, int out_size, void* d_ws, size_t ws_size,
                              hipStream_t stream) {
    const float* x      = (const float*)d_in[0];
    const float* logits = (const float*)d_in[1];
    float* out = (float*)d_out;

    // Dispatch TWICE (see header): marginal cost of the 2nd dispatch
    // isolates true kernel time from fixed per-replay overhead.
    sumconv_mfma<<<NN * (HH / 2), 256, 0, stream>>>(x, logits, out);
    sumconv_mfma<<<NN * (HH / 2), 256, 0, stream>>>(x, logits, out);
}

// Round 11
// 13.421 us; speedup vs baseline: 1.7091x; 1.7091x over previous
//
#include <hip/hip_runtime.h>
#include <math.h>

// Problem constants: N=32, CI=32, CO=32, H=64, W=64, K=2
#define NN 32
#define CI 32
#define CO 32
#define HH 64
#define WW 64
#define PLANE (HH * WW)

typedef __attribute__((ext_vector_type(8))) short bf16x8;   // MFMA A/B frag
typedef __attribute__((ext_vector_type(4))) float f32x4;    // MFMA C/D frag
typedef float v2f __attribute__((ext_vector_type(2)));

// float -> bf16 (round-to-nearest-even)
__device__ inline short f2bf(float f) {
    union { float f; unsigned u; } v; v.f = f;
    unsigned r = v.u + 0x7FFFu + ((v.u >> 16) & 1u);
    return (short)(r >> 16);
}

// ---------------------------------------------------------------------------
// out[n,co,h,w] = log( sum_ci W[co,ci,par] * exp(x[n,ci,h,w]) ),
//   W = softmax(logits over ci), par = (h&1)*2 + (w&1).
//
// R10 probe: fixed per-replay floor ~5.1us, kernel marginal ~8.9us -- ~2x my
// work model, and the only optimistic term was VMEM: the old wave=parity
// mapping made every x-load and out-store a stride-2 dword (50% sectors,
// 2x instructions). This version puts BOTH parities in-lane:
//
//   wave = (row pr, px-half u); lane loads float2 (column PAIR) ->
//   128B contiguous per 16 lanes, 8 loads/lane (was 16 scattered dwords).
//   Parities peel into the two B-frags; 4 MFMAs = 2 par x 2 co-half;
//   stores recombine as float2{even,odd} -> 8 coalesced stores (was 16).
//
// Rest = R9: x-loads issued first (fly during phase0; lgkmcnt-domain LDS
// weights don't drain them), phase0 softmax w/o max-pass -> bf16 LDS,
// A-frag = ds_read_b128, D: col=l15, row=4*kb+reg (HW-validated).
// XCD swizzle: XCD k owns images 4k..4k+3 (2 MB slab, L2-resident).
// ---------------------------------------------------------------------------
__global__ __launch_bounds__(256, 4) void sumconv_mfma(
        const float* __restrict__ x,
        const float* __restrict__ logits,
        float* __restrict__ out) {
    const int b = blockIdx.x;                     // 0..1023
    const int n = (b & 7) * 4 + ((b >> 3) & 3);   // image (XCD-chunked)
    const int r = b >> 5;                         // row-pair 0..31

    const int t    = threadIdx.x;
    const int wave = t >> 6;                      // 0..3
    const int lane = t & 63;
    const int pr = wave >> 1;                     // row within pair
    const int u  = wave & 1;                      // px half (cols 32u..32u+31)
    const int l15 = lane & 15, kb = lane >> 4;
    const int h = 2 * r + pr;

    __shared__ short Wl[4][CO * CI];              // bf16 weights [par][co*32+ci], 8 KB

    // ---- x loads first: 8 coalesced float2 (both parities per lane) ----
    const float* xp = x + ((n * CI + kb * 8) * HH + h) * WW + 32 * u + 2 * l15;
    float2 xv[8];
#pragma unroll
    for (int i = 0; i < 8; ++i) xv[i] = *(const float2*)(xp + i * PLANE);

    // ---- phase 0: softmax -> LDS bf16 (128 active threads) ----
    if (t < 128) {
        const int co = t >> 2, par = t & 3;
        const float* base = logits + (co * CI) * 4 + par;
        float e[CI];
        float ssum = 0.0f;
#pragma unroll
        for (int ci = 0; ci < CI; ++ci) { e[ci] = __expf(base[ci * 4]); ssum += e[ci]; }
        const float inv = 1.0f / ssum;
#pragma unroll
        for (int ci = 0; ci < CI; ++ci) Wl[par][co * CI + ci] = f2bf(e[ci] * inv);
    }
    __syncthreads();

    // ---- A-frags: parities 2*pr (even col) and 2*pr+1 (odd col) ----
    const int parE = 2 * pr, parO = 2 * pr + 1;
    const bf16x8 aE0 = *(const bf16x8*)&Wl[parE][(l15     ) * CI + kb * 8];
    const bf16x8 aE1 = *(const bf16x8*)&Wl[parE][(l15 + 16) * CI + kb * 8];
    const bf16x8 aO0 = *(const bf16x8*)&Wl[parO][(l15     ) * CI + kb * 8];
    const bf16x8 aO1 = *(const bf16x8*)&Wl[parO][(l15 + 16) * CI + kb * 8];

    // ---- exp(x) -> B-frags (even / odd parity) ----
    bf16x8 bE, bO;
#pragma unroll
    for (int i = 0; i < 8; ++i) {
        bE[i] = f2bf(__expf(xv[i].x));
        bO[i] = f2bf(__expf(xv[i].y));
    }

    // ---- 4 MFMAs: 2 parities x 2 co-halves (K=32) ----
    const f32x4 z = {0.f, 0.f, 0.f, 0.f};
    f32x4 cE0 = __builtin_amdgcn_mfma_f32_16x16x32_bf16(aE0, bE, z, 0, 0, 0);
    f32x4 cE1 = __builtin_amdgcn_mfma_f32_16x16x32_bf16(aE1, bE, z, 0, 0, 0);
    f32x4 cO0 = __builtin_amdgcn_mfma_f32_16x16x32_bf16(aO0, bO, z, 0, 0, 0);
    f32x4 cO1 = __builtin_amdgcn_mfma_f32_16x16x32_bf16(aO1, bO, z, 0, 0, 0);

    // ---- log + paired float2 stores. D: col(pair)=l15, row(co)=4*kb+reg ----
    const int wc = 32 * u + 2 * l15;
    float* ob = out + ((n * CO + 4 * kb) * HH + h) * WW + wc;   // co base 4*kb
#pragma unroll
    for (int reg = 0; reg < 4; ++reg) {
        v2f lo, hi;
        lo.x = __logf(cE0[reg]); lo.y = __logf(cO0[reg]);       // co = 4kb+reg
        hi.x = __logf(cE1[reg]); hi.y = __logf(cO1[reg]);       // co = 16+4kb+reg
        *(v2f*)(ob + (reg     ) * PLANE) = lo;
        *(v2f*)(ob + (reg + 16) * PLANE) = hi;
    }
}

extern "C" void kernel_launch(void* const* d_in, const int* in_sizes, int n_in,
                              void* d_out, int out_size, void* d_ws, size_t ws_size,
                              hipStream_t stream) {
    const float* x      = (const float*)d_in[0];
    const float* logits = (const float*)d_in[1];
    float* out = (float*)d_out;

    sumconv_mfma<<<NN * (HH / 2), 256, 0, stream>>>(x, logits, out);
}